// Round 1
// 1198.388 us; speedup vs baseline: 1.1958x; 1.1958x over previous
//
#include <hip/hip_runtime.h>
#include <hip/hip_bf16.h>

typedef __attribute__((ext_vector_type(8))) short short8;
typedef __attribute__((ext_vector_type(4))) float f32x4;
typedef __attribute__((ext_vector_type(4))) unsigned int uint4v;

#define BM 256
#define BN 256
#define BK 64

// async global->LDS, 16B per lane. LDS dest must be wave-uniform base + lane*16.
__device__ __forceinline__ void gl_lds16(const __hip_bfloat16* g, __hip_bfloat16* l) {
  __builtin_amdgcn_global_load_lds((const __attribute__((address_space(1))) void*)g,
                                   (__attribute__((address_space(3))) void*)l,
                                   16, 0, 0);
}

// Dequant qweight [K/8, N] int4-packed -> W' in 16B-chunk layout: chunk (kc, n)
// = W^T[n][kc*8 .. kc*8+8) stored at chunk index kc*N + n.
__global__ void dequant_kernel(const int* __restrict__ qweight,
                               const int* __restrict__ qzeros,
                               const float* __restrict__ scales,
                               __hip_bfloat16* __restrict__ wp, int N, int K) {
  const int n = blockIdx.x * 256 + threadIdx.x;   // N % 256 == 0
  const int kc = blockIdx.y;                      // qweight row = k/8
  const int g = kc >> 4;                          // (kc*8)/128
  const float s = scales[(size_t)g * N + n];
  const int zq = qzeros[(size_t)g * (N >> 3) + (n >> 3)];
  const float c = s * (float)((zq >> ((n & 7) * 4)) & 15);
  const int q = qweight[(size_t)kc * N + n];
  __hip_bfloat16 v[8];
#pragma unroll
  for (int j = 0; j < 8; j++)
    v[j] = __float2bfloat16(fmaf(s, (float)((q >> (4 * j)) & 15), -c));
  ((uint4v*)wp)[(size_t)kc * N + n] = *(const uint4v*)v;
}

// x fp32 [M,K] -> bf16 chunk layout X': chunk (kc, m) at index kc*M + m.
__global__ void cvtx_kernel(const float* __restrict__ x,
                            __hip_bfloat16* __restrict__ xp, int M, int K) {
  __shared__ __hip_bfloat16 tile[64 * 64];  // slot = c8*64 + m_local, 8 bf16/slot
  const int t = threadIdx.x;
  const int m0 = blockIdx.x * 64, k0 = blockIdx.y * 64;
  const int mr = t >> 2, cq = t & 3;  // 4 threads/row, 16 fp32 each
  const float4* src = (const float4*)(x + (size_t)(m0 + mr) * K + k0 + cq * 16);
  const float4 a = src[0], b = src[1], c = src[2], d = src[3];
  __hip_bfloat16 v[16];
  v[0] = __float2bfloat16(a.x);  v[1] = __float2bfloat16(a.y);
  v[2] = __float2bfloat16(a.z);  v[3] = __float2bfloat16(a.w);
  v[4] = __float2bfloat16(b.x);  v[5] = __float2bfloat16(b.y);
  v[6] = __float2bfloat16(b.z);  v[7] = __float2bfloat16(b.w);
  v[8] = __float2bfloat16(c.x);  v[9] = __float2bfloat16(c.y);
  v[10] = __float2bfloat16(c.z); v[11] = __float2bfloat16(c.w);
  v[12] = __float2bfloat16(d.x); v[13] = __float2bfloat16(d.y);
  v[14] = __float2bfloat16(d.z); v[15] = __float2bfloat16(d.w);
  *(uint4v*)&tile[((cq * 2 + 0) * 64 + mr) * 8] = *(const uint4v*)&v[0];
  *(uint4v*)&tile[((cq * 2 + 1) * 64 + mr) * 8] = *(const uint4v*)&v[8];
  __syncthreads();
#pragma unroll
  for (int j = 0; j < 2; j++) {
    const int s = j * 256 + t;
    const int c8 = s >> 6, m = s & 63;
    ((uint4v*)xp)[(size_t)((k0 >> 3) + c8) * M + m0 + m] = *(const uint4v*)&tile[s * 8];
  }
}

// 256x256 8-phase bf16 GEMM on chunk-transposed operands: C = X W^T + bias.
// 8 waves (2M x 4N), per-wave 128x64 output, BK=64, double-buffered 128KiB LDS.
// Chunk-major LDS (slot = c8*256 + row) is bank-conflict-free for ds_read_b128
// (measured 0 conflicts) AND gives linear global_load_lds staging -> no swizzle.
// Schedule per K-tile t (4 phases; staging ledger: [t+1.h3, t+2.h0, t+2.h2, t+2.h1],
// halves h0=A.ks0 h1=A.ks1 h2=B.ks0 h3=B.ks1; counted vmcnt(6) once per tile):
//   phase: {ds_read frags ; issue 1 half-tile stage ; s_barrier ; lgkmcnt(0) ;
//           setprio(1) 16xMFMA setprio(0) ; s_barrier}
// Overwrite safety: a region staged in phase p was last ds_read in phase p-1 or
// earlier; the end-of-phase barrier (reads landed in regs before it) orders them.
__global__ __launch_bounds__(512, 2) void gemm_kernel(
    const __hip_bfloat16* __restrict__ Xp,  // chunks [K/8][M]
    const __hip_bfloat16* __restrict__ Wp,  // chunks [K/8][N]
    const float* __restrict__ bias,
    float* __restrict__ C, int M, int N, int K) {
  __shared__ __hip_bfloat16 As[2][8 * 256 * 8];  // 32KB per buf
  __shared__ __hip_bfloat16 Bs[2][8 * 256 * 8];  // total 128KB
  const int tid = threadIdx.x;
  const int m0 = blockIdx.x * BM;  // x fastest => consecutive blocks share n0
  const int n0 = blockIdx.y * BN;
  const int wid = tid >> 6, ln = tid & 63;
  const int wmoff = (wid >> 2) * 128;  // 2 waves in M
  const int wnoff = (wid & 3) * 64;    // 4 waves in N
  const int lr = ln & 15, q4 = ln >> 4;

  f32x4 acc[8][4] = {};
  const int NT = K >> 6;  // K-tiles of 64

  auto stageA = [&](int t, int hs, int buf) {
#pragma unroll
    for (int i = 0; i < 2; ++i) {
      const int s = i * 512 + tid;
      const int c8 = (hs << 2) + (s >> 8);
      const int row = s & 255;
      gl_lds16(Xp + ((size_t)(t * 8 + c8) * M + m0 + row) * 8,
               &As[buf][(c8 * 256 + row) * 8]);
    }
  };
  auto stageB = [&](int t, int hs, int buf) {
#pragma unroll
    for (int i = 0; i < 2; ++i) {
      const int s = i * 512 + tid;
      const int c8 = (hs << 2) + (s >> 8);
      const int row = s & 255;
      gl_lds16(Wp + ((size_t)(t * 8 + c8) * N + n0 + row) * 8,
               &Bs[buf][(c8 * 256 + row) * 8]);
    }
  };

  // Prologue: tile0 all 4 halves, tile1 h0,h2,h1 (h3 comes in tile0.phase0).
  stageA(0, 0, 0); stageA(0, 1, 0); stageB(0, 0, 0); stageB(0, 1, 0);
  if (NT > 1) {
    stageA(1, 0, 1); stageB(1, 0, 1); stageA(1, 1, 1);
    asm volatile("s_waitcnt vmcnt(6)" ::: "memory");  // tile0's 8 loads retired
  } else {
    asm volatile("s_waitcnt vmcnt(0)" ::: "memory");
  }
  __builtin_amdgcn_s_barrier();

  short8 af[8], bf[2];

  for (int t = 0; t < NT; ++t) {
    const int cur = t & 1, nxt = cur ^ 1;
    const __hip_bfloat16* Ac = As[cur];
    const __hip_bfloat16* Bc = Bs[cur];

    // -- phase 0: A.ks0 (8 reads) + B.ks0.nh0 (2); stage (t+1).h3 -> nxt
#pragma unroll
    for (int mf = 0; mf < 8; ++mf)
      af[mf] = *(const short8*)&Ac[(q4 * 256 + wmoff + mf * 16 + lr) * 8];
#pragma unroll
    for (int j = 0; j < 2; ++j)
      bf[j] = *(const short8*)&Bc[(q4 * 256 + wnoff + j * 16 + lr) * 8];
    if (t + 1 < NT) stageB(t + 1, 1, nxt);
    __builtin_amdgcn_s_barrier();
    asm volatile("s_waitcnt lgkmcnt(0)" ::: "memory");
    __builtin_amdgcn_s_setprio(1);
#pragma unroll
    for (int mf = 0; mf < 8; ++mf) {
      acc[mf][0] = __builtin_amdgcn_mfma_f32_16x16x32_bf16(af[mf], bf[0], acc[mf][0], 0, 0, 0);
      acc[mf][1] = __builtin_amdgcn_mfma_f32_16x16x32_bf16(af[mf], bf[1], acc[mf][1], 0, 0, 0);
    }
    __builtin_amdgcn_s_setprio(0);
    __builtin_amdgcn_s_barrier();

    // -- phase 1: B.ks0.nh1 (2 reads); stage (t+2).h0 -> cur (A.ks0: last read ph0)
#pragma unroll
    for (int j = 0; j < 2; ++j)
      bf[j] = *(const short8*)&Bc[(q4 * 256 + wnoff + (2 + j) * 16 + lr) * 8];
    if (t + 2 < NT) stageA(t + 2, 0, cur);
    __builtin_amdgcn_s_barrier();
    asm volatile("s_waitcnt lgkmcnt(0)" ::: "memory");
    __builtin_amdgcn_s_setprio(1);
#pragma unroll
    for (int mf = 0; mf < 8; ++mf) {
      acc[mf][2] = __builtin_amdgcn_mfma_f32_16x16x32_bf16(af[mf], bf[0], acc[mf][2], 0, 0, 0);
      acc[mf][3] = __builtin_amdgcn_mfma_f32_16x16x32_bf16(af[mf], bf[1], acc[mf][3], 0, 0, 0);
    }
    __builtin_amdgcn_s_setprio(0);
    __builtin_amdgcn_s_barrier();

    // -- phase 2: A.ks1 (8) + B.ks1.nh0 (2); stage (t+2).h2 -> cur (B.ks0: last read ph1)
#pragma unroll
    for (int mf = 0; mf < 8; ++mf)
      af[mf] = *(const short8*)&Ac[((4 + q4) * 256 + wmoff + mf * 16 + lr) * 8];
#pragma unroll
    for (int j = 0; j < 2; ++j)
      bf[j] = *(const short8*)&Bc[((4 + q4) * 256 + wnoff + j * 16 + lr) * 8];
    if (t + 2 < NT) stageB(t + 2, 0, cur);
    __builtin_amdgcn_s_barrier();
    asm volatile("s_waitcnt lgkmcnt(0)" ::: "memory");
    __builtin_amdgcn_s_setprio(1);
#pragma unroll
    for (int mf = 0; mf < 8; ++mf) {
      acc[mf][0] = __builtin_amdgcn_mfma_f32_16x16x32_bf16(af[mf], bf[0], acc[mf][0], 0, 0, 0);
      acc[mf][1] = __builtin_amdgcn_mfma_f32_16x16x32_bf16(af[mf], bf[1], acc[mf][1], 0, 0, 0);
    }
    __builtin_amdgcn_s_setprio(0);
    __builtin_amdgcn_s_barrier();

    // -- phase 3: B.ks1.nh1 (2); stage (t+2).h1 -> cur (A.ks1: last read ph2);
    //    counted vmcnt once per K-tile: newest 6 loads are (t+2).h0/h2/h1 ->
    //    everything of tile t+1 is retired. Drain fully only before last tile.
#pragma unroll
    for (int j = 0; j < 2; ++j)
      bf[j] = *(const short8*)&Bc[((4 + q4) * 256 + wnoff + (2 + j) * 16 + lr) * 8];
    if (t + 2 < NT) stageA(t + 2, 1, cur);
    if (t == NT - 2) asm volatile("s_waitcnt vmcnt(0)" ::: "memory");
    else             asm volatile("s_waitcnt vmcnt(6)" ::: "memory");
    __builtin_amdgcn_s_barrier();
    asm volatile("s_waitcnt lgkmcnt(0)" ::: "memory");
    __builtin_amdgcn_s_setprio(1);
#pragma unroll
    for (int mf = 0; mf < 8; ++mf) {
      acc[mf][2] = __builtin_amdgcn_mfma_f32_16x16x32_bf16(af[mf], bf[0], acc[mf][2], 0, 0, 0);
      acc[mf][3] = __builtin_amdgcn_mfma_f32_16x16x32_bf16(af[mf], bf[1], acc[mf][3], 0, 0, 0);
    }
    __builtin_amdgcn_s_setprio(0);
    __builtin_amdgcn_s_barrier();
  }

  // C/D layout: col = lane&15, row = (lane>>4)*4 + reg  [m89/m91-verified]
  const int cr = m0 + wmoff + q4 * 4;
  const int cc = n0 + wnoff + lr;
#pragma unroll
  for (int nf = 0; nf < 4; ++nf) {
    const float bv = bias[cc + nf * 16];
#pragma unroll
    for (int mf = 0; mf < 8; ++mf) {
#pragma unroll
      for (int r = 0; r < 4; ++r) {
        C[(size_t)(cr + mf * 16 + r) * N + cc + nf * 16] = acc[mf][nf][r] + bv;
      }
    }
  }
}

// Correct-but-slow fallback if workspace/shapes don't conform (diagnostic path).
__global__ void naive_kernel(const float* __restrict__ x, const int* __restrict__ qweight,
                             const int* __restrict__ qzeros, const float* __restrict__ scales,
                             const float* __restrict__ bias, const int* __restrict__ g_idx,
                             float* __restrict__ out, int in_f, int out_f) {
  const int n = blockIdx.x * blockDim.x + threadIdx.x;
  if (n >= out_f) return;
  const int m = blockIdx.y;
  const float* xr = x + (size_t)m * in_f;
  float acc = 0.f;
  for (int kk = 0; kk < (in_f >> 3); kk++) {
    const int q = qweight[(size_t)kk * out_f + n];
    const int g = g_idx[kk * 8];
    const float s = scales[(size_t)g * out_f + n];
    const int z = (qzeros[(size_t)g * (out_f >> 3) + (n >> 3)] >> ((n & 7) * 4)) & 15;
    float part = 0.f;
#pragma unroll
    for (int j = 0; j < 8; j++)
      part += xr[kk * 8 + j] * (float)(((q >> (4 * j)) & 15) - z);
    acc += s * part;
  }
  out[(size_t)m * out_f + n] = acc + bias[n];
}

extern "C" void kernel_launch(void* const* d_in, const int* in_sizes, int n_in,
                              void* d_out, int out_size, void* d_ws, size_t ws_size,
                              hipStream_t stream) {
  const float* x = (const float*)d_in[0];
  const int* qweight = (const int*)d_in[1];
  const int* qzeros = (const int*)d_in[2];
  const float* scales = (const float*)d_in[3];
  const float* bias = (const float*)d_in[4];
  const int* g_idx = (const int*)d_in[5];
  float* out = (float*)d_out;

  const int out_f = in_sizes[4];          // bias length (N)
  const int in_f = in_sizes[5];           // g_idx length (K)
  const int tokens = in_sizes[0] / in_f;  // x rows (M)

  const size_t need_w = (size_t)in_f * out_f * sizeof(__hip_bfloat16);
  const size_t need_x = (size_t)tokens * in_f * sizeof(__hip_bfloat16);

  if (ws_size >= need_w + need_x && (in_f % 128) == 0 && (out_f % 256) == 0 &&
      (tokens % 256) == 0) {
    __hip_bfloat16* wp = (__hip_bfloat16*)d_ws;
    __hip_bfloat16* xp = (__hip_bfloat16*)((char*)d_ws + need_w);
    dequant_kernel<<<dim3(out_f / 256, in_f / 8), 256, 0, stream>>>(
        qweight, qzeros, scales, wp, out_f, in_f);
    cvtx_kernel<<<dim3(tokens / 64, in_f / 64), 256, 0, stream>>>(x, xp, tokens, in_f);
    gemm_kernel<<<dim3(tokens / BM, out_f / BN), 512, 0, stream>>>(
        xp, wp, bias, out, tokens, out_f, in_f);
  } else {
    naive_kernel<<<dim3((out_f + 255) / 256, tokens), 256, 0, stream>>>(
        x, qweight, qzeros, scales, bias, g_idx, out, in_f, out_f);
  }
}